// Round 6
// baseline (977.379 us; speedup 1.0000x reference)
//
#include <hip/hip_runtime.h>

#define N_NODES 50000
#define NEDGE   800000
#define HID     128
#define LDSP    129          // doubles per LDS row

// ---- workspace layout (units: doubles) ----
#define W1D_OFF 0            // 257*128 = 32896, row-major [k][j]
#define B1D_OFF 32896        // 128
#define W2D_OFF 33024        // 128*128 = 16384
#define B2D_OFF 49408        // 128
#define W3D_OFF 49536        // 128
#define B3D_OFF 49664        // 1
#define NWCONV  49665
#define PQ_OFF  49672        // 16B-aligned; P then Q, each 50000*128

// ---------------------------------------------------------------------------
// Kernel 0: convert all weights to fp64 once per call (ws re-poisoned).
// ---------------------------------------------------------------------------
__global__ void conv_kernel(const float* __restrict__ w1, const float* __restrict__ b1,
                            const float* __restrict__ w2, const float* __restrict__ b2,
                            const float* __restrict__ w3, const float* __restrict__ b3,
                            double* __restrict__ wsd) {
    const int i = blockIdx.x * 256 + threadIdx.x;
    if (i >= NWCONV) return;
    float v;
    if      (i < B1D_OFF) v = w1[i];
    else if (i < W2D_OFF) v = b1[i - B1D_OFF];
    else if (i < B2D_OFF) v = w2[i - W2D_OFF];
    else if (i < W3D_OFF) v = b2[i - B2D_OFF];
    else if (i < B3D_OFF) v = w3[i - W3D_OFF];
    else                  v = b3[0];
    wsd[i] = (double)v;
}

// ---------------------------------------------------------------------------
// Kernel 1: P[n][j] = sum_k f[n][k] w1[k][j] (sel=0), Q with rows 128..255.
// fp64 accumulate; W1 via wave-uniform s_load of pre-converted doubles.
// ---------------------------------------------------------------------------
__global__ __launch_bounds__(512, 4)
void pq_kernel(const float* __restrict__ features,
               const double* __restrict__ wsd,
               double* __restrict__ P,
               double* __restrict__ Q) {
    __shared__ float fts[64 * 132];
    const int t  = threadIdx.x;
    const int n0 = blockIdx.x * 64;
    const int sel = blockIdx.y;

    {
        const int n = t & 63, q = t >> 6;
        const int gn = n0 + n;
        #pragma unroll
        for (int i = 0; i < 4; ++i) {
            const int k = q * 16 + i * 4;
            float4 f = make_float4(0.f, 0.f, 0.f, 0.f);
            if (gn < N_NODES) f = *(const float4*)(features + (size_t)gn * HID + k);
            *(float4*)(&fts[n * 132 + k]) = f;
        }
    }
    __syncthreads();

    const int l  = t & 63;
    const int wv = __builtin_amdgcn_readfirstlane(t >> 6);
    const int j0 = wv * 16;
    const double* wb = wsd + W1D_OFF + (size_t)(sel * 128) * HID + j0;

    double acc[16];
    #pragma unroll
    for (int c = 0; c < 16; ++c) acc[c] = 0.0;

    const float* frow = &fts[l * 132];
    for (int k = 0; k < 128; k += 4) {
        float4 f = *(const float4*)(frow + k);
        #pragma unroll
        for (int kk = 0; kk < 4; ++kk) {
            const double fv = (double)((&f.x)[kk]);
            const double* wr = wb + (size_t)(k + kk) * HID;   // uniform -> s_load
            #pragma unroll
            for (int c = 0; c < 16; ++c)
                acc[c] = fma(fv, wr[c], acc[c]);
        }
    }

    const int gn = n0 + l;
    if (gn < N_NODES) {
        double* dst = (sel ? Q : P) + (size_t)gn * HID + j0;
        #pragma unroll
        for (int c = 0; c < 16; c += 2)
            *(double2*)(dst + c) = make_double2(acc[c], acc[c + 1]);
    }
}

// ---------------------------------------------------------------------------
// Kernel 2: fp64 layer-2/3 (exact z), then FP32-GRANULAR epilogue that
// mirrors a numpy fp32 translation of the reference op-by-op:
//   - z32 = (float)z64
//   - exp/log emulated correctly-rounded-to-fp32 via fp64 libm
//   - segment sums SEQUENTIAL ASCENDING in edge order (np.add.at semantics)
//   - sigmoid = 1/(1+exp(-x)) (scipy.expit form)
//   - decision fl32(fl32(y-thre)+1e-7f) > 0
// ---------------------------------------------------------------------------
__global__ __launch_bounds__(512, 4)
void edge_kernel(const int*   __restrict__ indices,
                 const float* __restrict__ values,
                 const float* __restrict__ tempr,
                 const double* __restrict__ wsd,
                 const double* __restrict__ P,
                 const double* __restrict__ Q,
                 float* __restrict__ out) {
    __shared__ double h1s[64 * LDSP];
    __shared__ double zpart[8][64];
    const int t  = threadIdx.x;
    const int e0 = blockIdx.x * 64;

    // ---- stage h1 (fp64) ----
    {
        const int e = t & 63, q = t >> 6;
        const int ge = e0 + e;
        const int row = indices[ge];
        const int col = indices[NEDGE + ge];
        const double v = (double)values[ge];
        const double* prow = P + (size_t)row * HID + q * 16;
        const double* qrow = Q + (size_t)col * HID + q * 16;
        const double* w1c  = wsd + W1D_OFF + (size_t)256 * HID + q * 16;
        const double* b1d  = wsd + B1D_OFF + q * 16;
        double* hdst = &h1s[e * LDSP + q * 16];
        #pragma unroll
        for (int i = 0; i < 16; i += 2) {
            double2 p  = *(const double2*)(prow + i);
            double2 qq = *(const double2*)(qrow + i);
            hdst[i]     = fmax(fma(v, w1c[i],     p.x + qq.x) + b1d[i],     0.0);
            hdst[i + 1] = fmax(fma(v, w1c[i + 1], p.y + qq.y) + b1d[i + 1], 0.0);
        }
    }
    __syncthreads();

    // ---- layer-2: lane = edge, wave = 16 cols (W2 fp64 via s_load) ----
    const int l  = t & 63;
    const int wv = __builtin_amdgcn_readfirstlane(t >> 6);
    const int j0 = wv * 16;
    const double* w2b = wsd + W2D_OFF + j0;

    double acc[16];
    #pragma unroll
    for (int c = 0; c < 16; ++c) acc[c] = 0.0;

    const double* hrow = &h1s[l * LDSP];
    for (int k = 0; k < 128; k += 2) {
        const double h0 = hrow[k];
        const double h1v = hrow[k + 1];
        const double* wr0 = w2b + (size_t)k * HID;
        const double* wr1 = wr0 + HID;
        #pragma unroll
        for (int c = 0; c < 16; ++c) acc[c] = fma(h0,  wr0[c], acc[c]);
        #pragma unroll
        for (int c = 0; c < 16; ++c) acc[c] = fma(h1v, wr1[c], acc[c]);
    }

    {
        const double* b2d = wsd + B2D_OFF + j0;
        const double* w3d = wsd + W3D_OFF + j0;
        double part = 0.0;
        #pragma unroll
        for (int c = 0; c < 16; ++c) {
            const double h2 = fmax(acc[c] + b2d[c], 0.0);
            part = fma(h2, w3d[c], part);
        }
        zpart[wv][l] = part;
    }
    __syncthreads();

    // ---- FP32-granular epilogue: 4 nodes x 16 edges in wave 0 ----
    if (t < 64) {
        double z64 = wsd[B3D_OFF];
        #pragma unroll
        for (int w = 0; w < 8; ++w) z64 += zpart[w][t];
        const float z = (float)z64;                     // ref z is fp32

        const float T = tempr[0];
        const int base = t & 48;

        // softmax #1: max (exact), corr-rounded exp, SEQUENTIAL sum
        float m = z;
        #pragma unroll
        for (int d = 1; d < 16; d <<= 1) m = fmaxf(m, __shfl_xor(m, d));
        const float e1 = (float)exp((double)(z - m));
        float s = __shfl(e1, base);
        #pragma unroll
        for (int k = 1; k < 16; ++k) s += __shfl(e1, base + k);  // ascending
        const float pi = e1 / s;

        // hard-concrete, eval path
        const float lp = (float)log((double)(pi + 1e-8f));
        const float x  = lp / T;
        const float ex = (float)exp(-(double)x);        // x<0 always here
        float hard = 1.0f / (1.0f + ex);                // expit form
        hard = fminf(fmaxf(hard, 0.0f), 1.0f);          // clip (no-op)

        // softmax #2
        float m2 = hard;
        #pragma unroll
        for (int d = 1; d < 16; d <<= 1) m2 = fmaxf(m2, __shfl_xor(m2, d));
        const float e2 = (float)exp((double)(hard - m2));
        float s2 = __shfl(e2, base);
        #pragma unroll
        for (int k = 1; k < 16; ++k) s2 += __shfl(e2, base + k); // ascending
        const float y = e2 / s2;

        // rank-8 threshold (multiset rank selection == stable-sort pos 7)
        int cgt = 0, ceq = 0;
        #pragma unroll
        for (int j = 0; j < 16; ++j) {
            const float yj = __shfl(y, base + j);
            cgt += (yj > y);
            ceq += (yj == y);
        }
        float cand = (cgt <= 7 && cgt + ceq >= 8) ? y : -3.0e38f;
        float thre = cand;
        #pragma unroll
        for (int d = 1; d < 16; d <<= 1) thre = fmaxf(thre, __shfl_xor(thre, d));

        const float g = (y - thre) + 1e-7f;             // fl32 order as in ref
        out[e0 + t] = (g > 0.0f) ? y : 0.0f;
    }
}

// ---------------------------------------------------------------------------
extern "C" void kernel_launch(void* const* d_in, const int* in_sizes, int n_in,
                              void* d_out, int out_size, void* d_ws, size_t ws_size,
                              hipStream_t stream) {
    const float* features = (const float*)d_in[0];
    const int*   indices  = (const int*)  d_in[1];
    const float* values   = (const float*)d_in[2];
    const float* tempr    = (const float*)d_in[3];
    const float* w1       = (const float*)d_in[4];
    const float* b1       = (const float*)d_in[5];
    const float* w2       = (const float*)d_in[6];
    const float* b2       = (const float*)d_in[7];
    const float* w3       = (const float*)d_in[8];
    const float* b3       = (const float*)d_in[9];
    float* out = (float*)d_out;

    double* wsd = (double*)d_ws;
    double* P = wsd + PQ_OFF;                     // [N][128] fp64
    double* Q = P + (size_t)N_NODES * HID;        // [N][128] fp64

    conv_kernel<<<(NWCONV + 255) / 256, 256, 0, stream>>>(w1, b1, w2, b2, w3, b3, wsd);

    dim3 g1((N_NODES + 63) / 64, 2);
    pq_kernel<<<g1, 512, 0, stream>>>(features, wsd, P, Q);

    dim3 g2(NEDGE / 64);
    edge_kernel<<<g2, 512, 0, stream>>>(indices, values, tempr, wsd, P, Q, out);
}